// Round 4
// baseline (33.783 us; speedup 1.0000x reference)
//
#include <hip/hip_runtime.h>
#include <hip/hip_bf16.h>

#define BATCH 16384
#define HIST  50

// DPP row_ror (16-lane row scope) reduction — pure VALU, no LDS pipe.
template<int CTRL>
__device__ __forceinline__ float dpp_mov(float x) {
    return __builtin_bit_cast(float,
        __builtin_amdgcn_update_dpp(0, __builtin_bit_cast(int, x),
                                    CTRL, 0xF, 0xF, true));
}
__device__ __forceinline__ float red16_add(float x) {
    x += dpp_mov<0x128>(x);   // row_ror:8
    x += dpp_mov<0x124>(x);   // row_ror:4
    x += dpp_mov<0x122>(x);   // row_ror:2
    x += dpp_mov<0x121>(x);   // row_ror:1
    return x;
}
__device__ __forceinline__ float red16_max(float x) {
    x = fmaxf(x, dpp_mov<0x128>(x));
    x = fmaxf(x, dpp_mov<0x124>(x));
    x = fmaxf(x, dpp_mov<0x122>(x));
    x = fmaxf(x, dpp_mov<0x121>(x));
    return x;
}
__device__ __forceinline__ float dot4(float4 a, float4 b) {
    return a.x*b.x + a.y*b.y + a.z*b.z + a.w*b.w;
}

// One 64-lane wave per batch element; 4 groups of 16 lanes; group g handles
// 13/13/12/12 history rows with coalesced float4 row loads.
// out[b] = sigmoid( sum_l z_l*w_l + u_e.y_e ), z = softmax(w)
__global__ __launch_bounds__(256, 8) void RUM_72980084294375_kernel(
    const int* __restrict__ u, const int* __restrict__ X, const int* __restrict__ y,
    const float* __restrict__ item_emb, const float* __restrict__ user_emb,
    float* __restrict__ out)
{
    __shared__ int sX[4 * HIST];

    const int tid  = threadIdx.x;
    const int b0   = blockIdx.x * 4;

    if (tid < 4 * HIST) sX[tid] = X[b0 * HIST + tid];   // coalesced staging
    __syncthreads();

    const int wave   = tid >> 6;          // batch element within block
    const int lane   = tid & 63;
    const int lane16 = lane & 15;
    const int g      = lane >> 4;         // group 0..3
    const int b      = __builtin_amdgcn_readfirstlane(b0 + wave);

    const float4* item4 = reinterpret_cast<const float4*>(item_emb);
    const float4* user4 = reinterpret_cast<const float4*>(user_emb);

    const int yi = y[b];                  // wave-uniform scalar loads
    const int ui = u[b];
    const float4 y4 = item4[(size_t)yi * 16 + lane16];
    const float4 u4 = user4[(size_t)ui * 16 + lane16];

    const float uy = red16_add(dot4(u4, y4));   // same in every group

    const int start = (g < 2) ? g * 13 : 26 + (g - 2) * 12;
    const int count = (g < 2) ? 13 : 12;
    const int* wX = sX + wave * HIST;

    // lane k of each group keeps w of its group's k-th item
    float wv = -1e30f;
    #pragma unroll
    for (int k = 0; k < 13; ++k) {
        const int idx = (k < count) ? wX[start + k] : 0;   // row 0 = zero pad
        const float4 x4 = item4[(size_t)idx * 16 + lane16];
        const float w = red16_add(dot4(x4, y4));
        if (k < count && lane16 == k) wv = w;
    }

    // max over 50: group reduce then cross-group
    float m = red16_max(wv);
    m = fmaxf(m, __shfl_xor(m, 16, 64));
    m = fmaxf(m, __shfl_xor(m, 32, 64));

    const float e = __expf(wv - m);       // invalid slots: exp(-1e30-m)=0
    float s = red16_add(e);
    float t = red16_add(e * wv);
    s += __shfl_xor(s, 16, 64);  s += __shfl_xor(s, 32, 64);
    t += __shfl_xor(t, 16, 64);  t += __shfl_xor(t, 32, 64);

    if (lane == 0) {
        const float logit = t / s + uy;
        out[b] = 1.0f / (1.0f + __expf(-logit));
    }
}

extern "C" void kernel_launch(void* const* d_in, const int* in_sizes, int n_in,
                              void* d_out, int out_size, void* d_ws, size_t ws_size,
                              hipStream_t stream) {
    const int*   u        = (const int*)d_in[0];
    const int*   X        = (const int*)d_in[1];
    const int*   y        = (const int*)d_in[2];
    const float* item_emb = (const float*)d_in[3];
    const float* user_emb = (const float*)d_in[4];
    float*       out      = (float*)d_out;

    const int blocks = BATCH / 4;   // 4096 blocks x 4 waves
    RUM_72980084294375_kernel<<<blocks, 256, 0, stream>>>(
        u, X, y, item_emb, user_emb, out);
}

// Round 5
// 28.358 us; speedup vs baseline: 1.1913x; 1.1913x over previous
//
#include <hip/hip_runtime.h>
#include <hip/hip_bf16.h>
#include <hip/hip_fp16.h>

#define BATCH 16384
#define HIST  50
#define ITEM_ROWS 100001
#define EMB   64

// DPP row_ror (16-lane row scope) reduction — pure VALU, no LDS pipe.
template<int CTRL>
__device__ __forceinline__ float dpp_mov(float x) {
    return __builtin_bit_cast(float,
        __builtin_amdgcn_update_dpp(0, __builtin_bit_cast(int, x),
                                    CTRL, 0xF, 0xF, true));
}
__device__ __forceinline__ float red16_add(float x) {
    x += dpp_mov<0x128>(x);   // row_ror:8
    x += dpp_mov<0x124>(x);   // row_ror:4
    x += dpp_mov<0x122>(x);   // row_ror:2
    x += dpp_mov<0x121>(x);   // row_ror:1
    return x;
}
__device__ __forceinline__ float red16_max(float x) {
    x = fmaxf(x, dpp_mov<0x128>(x));
    x = fmaxf(x, dpp_mov<0x124>(x));
    x = fmaxf(x, dpp_mov<0x122>(x));
    x = fmaxf(x, dpp_mov<0x121>(x));
    return x;
}
__device__ __forceinline__ float dot4(float4 a, float4 b) {
    return a.x*b.x + a.y*b.y + a.z*b.z + a.w*b.w;
}
// 4 halves (uint2) -> float4
__device__ __forceinline__ float4 h4_to_f4(uint2 h) {
    const float2 a = __half22float2(__builtin_bit_cast(__half2, h.x));
    const float2 b = __half22float2(__builtin_bit_cast(__half2, h.y));
    return make_float4(a.x, a.y, b.x, b.y);
}

// ---- kernel 1: fp32 item table -> fp16 table in workspace (streaming) ----
struct half8 { __half2 a, b, c, d; };   // 16 B
__global__ __launch_bounds__(256) void cvt_fp16_kernel(
    const float* __restrict__ in, half8* __restrict__ out, int n8)
{
    const int i = blockIdx.x * 256 + threadIdx.x;   // 8 elements per thread
    if (i >= n8) return;
    const float4* in4 = reinterpret_cast<const float4*>(in);
    const float4 x0 = in4[i * 2];
    const float4 x1 = in4[i * 2 + 1];
    half8 h;
    h.a = __floats2half2_rn(x0.x, x0.y);
    h.b = __floats2half2_rn(x0.z, x0.w);
    h.c = __floats2half2_rn(x1.x, x1.y);
    h.d = __floats2half2_rn(x1.z, x1.w);
    out[i] = h;
}

// ---- kernel 2 (fp16 path): one wave per batch element, 4 groups of 16 ----
// out[b] = sigmoid( sum_l z_l*w_l + u_e.y_e ), z = softmax(w)  [BETA=ALPHA=1]
__global__ __launch_bounds__(256, 8) void RUM_72980084294375_kernel(
    const int* __restrict__ u, const int* __restrict__ X, const int* __restrict__ y,
    const uint2* __restrict__ itemh, const float* __restrict__ user_emb,
    float* __restrict__ out)
{
    __shared__ int sX[4 * HIST];

    const int tid = threadIdx.x;
    const int b0  = blockIdx.x * 4;

    if (tid < 4 * HIST) sX[tid] = X[b0 * HIST + tid];   // coalesced staging
    __syncthreads();

    const int wave   = tid >> 6;
    const int lane   = tid & 63;
    const int lane16 = lane & 15;
    const int g      = lane >> 4;
    const int b      = __builtin_amdgcn_readfirstlane(b0 + wave);

    const float4* user4 = reinterpret_cast<const float4*>(user_emb);

    const int yi = y[b];                  // wave-uniform scalar loads
    const int ui = u[b];
    // fp16 row: 64 halves = 16 uint2 chunks; lane16 owns elems [4*lane16..+3]
    const uint2  y8 = itemh[(size_t)yi * 16 + lane16];
    const float4 yf = h4_to_f4(y8);
    const float4 u4 = user4[(size_t)ui * 16 + lane16];

    const float uy = red16_add(dot4(u4, yf));

    const int start = (g < 2) ? g * 13 : 26 + (g - 2) * 12;
    const int count = (g < 2) ? 13 : 12;
    const int* wX = sX + wave * HIST;

    float wv = -1e30f;
    #pragma unroll
    for (int k = 0; k < 13; ++k) {
        const int idx = (k < count) ? wX[start + k] : 0;   // row 0 = zeros
        const uint2 x8 = itemh[(size_t)idx * 16 + lane16]; // 8 B/lane, 128 B/row
        const float4 xf = h4_to_f4(x8);
        const float w = red16_add(dot4(xf, yf));
        if (k < count && lane16 == k) wv = w;
    }

    float m = red16_max(wv);
    m = fmaxf(m, __shfl_xor(m, 16, 64));
    m = fmaxf(m, __shfl_xor(m, 32, 64));

    const float e = __expf(wv - m);       // invalid slots: exp(-huge)=0
    float s = red16_add(e);
    float t = red16_add(e * wv);
    s += __shfl_xor(s, 16, 64);  s += __shfl_xor(s, 32, 64);
    t += __shfl_xor(t, 16, 64);  t += __shfl_xor(t, 32, 64);

    if (lane == 0) {
        const float logit = t / s + uy;
        out[b] = 1.0f / (1.0f + __expf(-logit));
    }
}

// ---- fp32 fallback (identical to R4 kernel) if ws is too small ----
__global__ __launch_bounds__(256, 8) void RUM_72980084294375_f32_kernel(
    const int* __restrict__ u, const int* __restrict__ X, const int* __restrict__ y,
    const float* __restrict__ item_emb, const float* __restrict__ user_emb,
    float* __restrict__ out)
{
    __shared__ int sX[4 * HIST];
    const int tid = threadIdx.x;
    const int b0  = blockIdx.x * 4;
    if (tid < 4 * HIST) sX[tid] = X[b0 * HIST + tid];
    __syncthreads();

    const int wave   = tid >> 6;
    const int lane   = tid & 63;
    const int lane16 = lane & 15;
    const int g      = lane >> 4;
    const int b      = __builtin_amdgcn_readfirstlane(b0 + wave);

    const float4* item4 = reinterpret_cast<const float4*>(item_emb);
    const float4* user4 = reinterpret_cast<const float4*>(user_emb);

    const int yi = y[b];
    const int ui = u[b];
    const float4 y4 = item4[(size_t)yi * 16 + lane16];
    const float4 u4 = user4[(size_t)ui * 16 + lane16];
    const float uy = red16_add(dot4(u4, y4));

    const int start = (g < 2) ? g * 13 : 26 + (g - 2) * 12;
    const int count = (g < 2) ? 13 : 12;
    const int* wX = sX + wave * HIST;

    float wv = -1e30f;
    #pragma unroll
    for (int k = 0; k < 13; ++k) {
        const int idx = (k < count) ? wX[start + k] : 0;
        const float4 x4 = item4[(size_t)idx * 16 + lane16];
        const float w = red16_add(dot4(x4, y4));
        if (k < count && lane16 == k) wv = w;
    }

    float m = red16_max(wv);
    m = fmaxf(m, __shfl_xor(m, 16, 64));
    m = fmaxf(m, __shfl_xor(m, 32, 64));

    const float e = __expf(wv - m);
    float s = red16_add(e);
    float t = red16_add(e * wv);
    s += __shfl_xor(s, 16, 64);  s += __shfl_xor(s, 32, 64);
    t += __shfl_xor(t, 16, 64);  t += __shfl_xor(t, 32, 64);

    if (lane == 0) {
        const float logit = t / s + uy;
        out[b] = 1.0f / (1.0f + __expf(-logit));
    }
}

extern "C" void kernel_launch(void* const* d_in, const int* in_sizes, int n_in,
                              void* d_out, int out_size, void* d_ws, size_t ws_size,
                              hipStream_t stream) {
    const int*   u        = (const int*)d_in[0];
    const int*   X        = (const int*)d_in[1];
    const int*   y        = (const int*)d_in[2];
    const float* item_emb = (const float*)d_in[3];
    const float* user_emb = (const float*)d_in[4];
    float*       out      = (float*)d_out;

    const size_t need = (size_t)ITEM_ROWS * EMB * sizeof(__half);  // 12.8 MB

    if (ws_size >= need) {
        const int n8 = ITEM_ROWS * EMB / 8;          // 800008 (divides exactly)
        cvt_fp16_kernel<<<(n8 + 255) / 256, 256, 0, stream>>>(
            item_emb, (half8*)d_ws, n8);
        RUM_72980084294375_kernel<<<BATCH / 4, 256, 0, stream>>>(
            u, X, y, (const uint2*)d_ws, user_emb, out);
    } else {
        RUM_72980084294375_f32_kernel<<<BATCH / 4, 256, 0, stream>>>(
            u, X, y, item_emb, user_emb, out);
    }
}

// Round 6
// 27.151 us; speedup vs baseline: 1.2443x; 1.0444x over previous
//
#include <hip/hip_runtime.h>
#include <hip/hip_bf16.h>
#include <hip/hip_fp16.h>

#define BATCH 16384
#define HIST  50
#define ITEM_ROWS 100001
#define EMB   64

typedef float v2f __attribute__((ext_vector_type(2)));

// DPP row_ror (16-lane row scope) reduction — pure VALU, no LDS pipe.
template<int CTRL>
__device__ __forceinline__ float dpp_mov(float x) {
    return __builtin_bit_cast(float,
        __builtin_amdgcn_update_dpp(0, __builtin_bit_cast(int, x),
                                    CTRL, 0xF, 0xF, true));
}
__device__ __forceinline__ float red16_add(float x) {
    x += dpp_mov<0x128>(x);   // row_ror:8
    x += dpp_mov<0x124>(x);   // row_ror:4
    x += dpp_mov<0x122>(x);   // row_ror:2
    x += dpp_mov<0x121>(x);   // row_ror:1
    return x;
}
__device__ __forceinline__ float red16_max(float x) {
    x = fmaxf(x, dpp_mov<0x128>(x));
    x = fmaxf(x, dpp_mov<0x124>(x));
    x = fmaxf(x, dpp_mov<0x122>(x));
    x = fmaxf(x, dpp_mov<0x121>(x));
    return x;
}
__device__ __forceinline__ float dot4(float4 a, float4 b) {
    return a.x*b.x + a.y*b.y + a.z*b.z + a.w*b.w;
}

// ---- kernel 1: fp32 item table -> fp8 e4m3 table in workspace ----
// 8 elements per thread: 2x float4 in, 8 B (uint2) out.
__global__ __launch_bounds__(256) void cvt_fp8_kernel(
    const float4* __restrict__ in4, uint2* __restrict__ out, int n8)
{
    const int i = blockIdx.x * 256 + threadIdx.x;
    if (i >= n8) return;
    const float4 x0 = in4[2 * i];
    const float4 x1 = in4[2 * i + 1];
    int p0 = 0, p1 = 0;
    p0 = __builtin_amdgcn_cvt_pk_fp8_f32(x0.x, x0.y, p0, false); // bytes 0,1
    p0 = __builtin_amdgcn_cvt_pk_fp8_f32(x0.z, x0.w, p0, true);  // bytes 2,3
    p1 = __builtin_amdgcn_cvt_pk_fp8_f32(x1.x, x1.y, p1, false);
    p1 = __builtin_amdgcn_cvt_pk_fp8_f32(x1.z, x1.w, p1, true);
    out[i] = make_uint2((unsigned)p0, (unsigned)p1);
}

// ---- kernel 2 (fp8 path): one wave per batch element, 4 groups of 16 ----
// x-rows: fp8 table (64 B/row = 1 cache line). y-rows, u-rows: original fp32.
// out[b] = sigmoid( sum_l z_l*w_l + u_e.y_e ), z = softmax(w)  [BETA=ALPHA=1]
__global__ __launch_bounds__(256, 8) void RUM_72980084294375_kernel(
    const int* __restrict__ u, const int* __restrict__ X, const int* __restrict__ y,
    const unsigned* __restrict__ item8, const float* __restrict__ item_emb,
    const float* __restrict__ user_emb, float* __restrict__ out)
{
    __shared__ int sX[4 * HIST];

    const int tid = threadIdx.x;
    const int b0  = blockIdx.x * 4;

    if (tid < 4 * HIST) sX[tid] = X[b0 * HIST + tid];   // coalesced staging
    __syncthreads();

    const int wave   = tid >> 6;
    const int lane   = tid & 63;
    const int lane16 = lane & 15;
    const int g      = lane >> 4;
    const int b      = __builtin_amdgcn_readfirstlane(b0 + wave);

    const float4* item4 = reinterpret_cast<const float4*>(item_emb);
    const float4* user4 = reinterpret_cast<const float4*>(user_emb);

    const int yi = y[b];                  // wave-uniform scalar loads
    const int ui = u[b];
    const float4 y4 = item4[(size_t)yi * 16 + lane16];  // fp32, coalesced
    const float4 u4 = user4[(size_t)ui * 16 + lane16];  // fp32, coalesced

    const float uy = red16_add(dot4(u4, y4));           // exact fp32 u.y

    const int start = (g < 2) ? g * 13 : 26 + (g - 2) * 12;
    const int count = (g < 2) ? 13 : 12;
    const int* wX = sX + wave * HIST;

    float wv = -1e30f;
    #pragma unroll
    for (int k = 0; k < 13; ++k) {
        const int idx = (k < count) ? wX[start + k] : 0;     // row 0 = zeros
        // 4 B/lane x 16 lanes = one 64 B line per row
        const unsigned q = item8[(size_t)idx * 16 + lane16];
        const v2f lo = __builtin_amdgcn_cvt_pk_f32_fp8((int)q, false);
        const v2f hi = __builtin_amdgcn_cvt_pk_f32_fp8((int)q, true);
        const float4 xf = make_float4(lo.x, lo.y, hi.x, hi.y);
        const float w = red16_add(dot4(xf, y4));
        if (k < count && lane16 == k) wv = w;
    }

    float m = red16_max(wv);
    m = fmaxf(m, __shfl_xor(m, 16, 64));
    m = fmaxf(m, __shfl_xor(m, 32, 64));

    const float e = __expf(wv - m);       // invalid slots: exp(-huge)=0
    float s = red16_add(e);
    float t = red16_add(e * wv);
    s += __shfl_xor(s, 16, 64);  s += __shfl_xor(s, 32, 64);
    t += __shfl_xor(t, 16, 64);  t += __shfl_xor(t, 32, 64);

    if (lane == 0) {
        const float logit = t / s + uy;
        out[b] = 1.0f / (1.0f + __expf(-logit));
    }
}

// ---- fp32 fallback if ws is too small ----
__global__ __launch_bounds__(256, 8) void RUM_72980084294375_f32_kernel(
    const int* __restrict__ u, const int* __restrict__ X, const int* __restrict__ y,
    const float* __restrict__ item_emb, const float* __restrict__ user_emb,
    float* __restrict__ out)
{
    __shared__ int sX[4 * HIST];
    const int tid = threadIdx.x;
    const int b0  = blockIdx.x * 4;
    if (tid < 4 * HIST) sX[tid] = X[b0 * HIST + tid];
    __syncthreads();

    const int wave   = tid >> 6;
    const int lane   = tid & 63;
    const int lane16 = lane & 15;
    const int g      = lane >> 4;
    const int b      = __builtin_amdgcn_readfirstlane(b0 + wave);

    const float4* item4 = reinterpret_cast<const float4*>(item_emb);
    const float4* user4 = reinterpret_cast<const float4*>(user_emb);

    const int yi = y[b];
    const int ui = u[b];
    const float4 y4 = item4[(size_t)yi * 16 + lane16];
    const float4 u4 = user4[(size_t)ui * 16 + lane16];
    const float uy = red16_add(dot4(u4, y4));

    const int start = (g < 2) ? g * 13 : 26 + (g - 2) * 12;
    const int count = (g < 2) ? 13 : 12;
    const int* wX = sX + wave * HIST;

    float wv = -1e30f;
    #pragma unroll
    for (int k = 0; k < 13; ++k) {
        const int idx = (k < count) ? wX[start + k] : 0;
        const float4 x4 = item4[(size_t)idx * 16 + lane16];
        const float w = red16_add(dot4(x4, y4));
        if (k < count && lane16 == k) wv = w;
    }

    float m = red16_max(wv);
    m = fmaxf(m, __shfl_xor(m, 16, 64));
    m = fmaxf(m, __shfl_xor(m, 32, 64));

    const float e = __expf(wv - m);
    float s = red16_add(e);
    float t = red16_add(e * wv);
    s += __shfl_xor(s, 16, 64);  s += __shfl_xor(s, 32, 64);
    t += __shfl_xor(t, 16, 64);  t += __shfl_xor(t, 32, 64);

    if (lane == 0) {
        const float logit = t / s + uy;
        out[b] = 1.0f / (1.0f + __expf(-logit));
    }
}

extern "C" void kernel_launch(void* const* d_in, const int* in_sizes, int n_in,
                              void* d_out, int out_size, void* d_ws, size_t ws_size,
                              hipStream_t stream) {
    const int*   u        = (const int*)d_in[0];
    const int*   X        = (const int*)d_in[1];
    const int*   y        = (const int*)d_in[2];
    const float* item_emb = (const float*)d_in[3];
    const float* user_emb = (const float*)d_in[4];
    float*       out      = (float*)d_out;

    const size_t need = (size_t)ITEM_ROWS * EMB;     // 6.4 MB fp8 table

    if (ws_size >= need) {
        const int n8 = ITEM_ROWS * EMB / 8;          // 800008 (divides exactly)
        cvt_fp8_kernel<<<(n8 + 255) / 256, 256, 0, stream>>>(
            (const float4*)item_emb, (uint2*)d_ws, n8);
        RUM_72980084294375_kernel<<<BATCH / 4, 256, 0, stream>>>(
            u, X, y, (const unsigned*)d_ws, item_emb, user_emb, out);
    } else {
        RUM_72980084294375_f32_kernel<<<BATCH / 4, 256, 0, stream>>>(
            u, X, y, item_emb, user_emb, out);
    }
}

// Round 7
// 24.757 us; speedup vs baseline: 1.3646x; 1.0967x over previous
//
#include <hip/hip_runtime.h>
#include <hip/hip_bf16.h>
#include <hip/hip_fp16.h>

#define BATCH 16384
#define HIST  50
#define ITEM_ROWS 100001
#define EMB   64

typedef float v2f __attribute__((ext_vector_type(2)));

// DPP row_ror (16-lane row scope) reduction — pure VALU, no LDS pipe.
template<int CTRL>
__device__ __forceinline__ float dpp_mov(float x) {
    return __builtin_bit_cast(float,
        __builtin_amdgcn_update_dpp(0, __builtin_bit_cast(int, x),
                                    CTRL, 0xF, 0xF, true));
}
__device__ __forceinline__ float red16_add(float x) {
    x += dpp_mov<0x128>(x);   // row_ror:8
    x += dpp_mov<0x124>(x);   // row_ror:4
    x += dpp_mov<0x122>(x);   // row_ror:2
    x += dpp_mov<0x121>(x);   // row_ror:1
    return x;
}
__device__ __forceinline__ float red16_max(float x) {
    x = fmaxf(x, dpp_mov<0x128>(x));
    x = fmaxf(x, dpp_mov<0x124>(x));
    x = fmaxf(x, dpp_mov<0x122>(x));
    x = fmaxf(x, dpp_mov<0x121>(x));
    return x;
}
__device__ __forceinline__ float dot4(float4 a, float4 b) {
    return a.x*b.x + a.y*b.y + a.z*b.z + a.w*b.w;
}

// ---- kernel 1: fp32 item table -> fp8 e4m3 table in workspace ----
__global__ __launch_bounds__(256) void cvt_fp8_kernel(
    const float4* __restrict__ in4, uint2* __restrict__ out, int n8)
{
    const int i = blockIdx.x * 256 + threadIdx.x;
    if (i >= n8) return;
    const float4 x0 = in4[2 * i];
    const float4 x1 = in4[2 * i + 1];
    int p0 = 0, p1 = 0;
    p0 = __builtin_amdgcn_cvt_pk_fp8_f32(x0.x, x0.y, p0, false);
    p0 = __builtin_amdgcn_cvt_pk_fp8_f32(x0.z, x0.w, p0, true);
    p1 = __builtin_amdgcn_cvt_pk_fp8_f32(x1.x, x1.y, p1, false);
    p1 = __builtin_amdgcn_cvt_pk_fp8_f32(x1.z, x1.w, p1, true);
    out[i] = make_uint2((unsigned)p0, (unsigned)p1);
}

// ---- kernel 2: one wave per batch element; all 13 row-loads in flight ----
// x-rows: fp8 table (64 B/row = 1 line). y/u rows: original fp32 (coalesced).
// out[b] = sigmoid( sum_l z_l*w_l + u_e.y_e ), z = softmax(w)  [BETA=ALPHA=1]
__global__ __launch_bounds__(256, 4) void RUM_72980084294375_kernel(
    const int* __restrict__ u, const int* __restrict__ X, const int* __restrict__ y,
    const unsigned* __restrict__ item8, const float* __restrict__ item_emb,
    const float* __restrict__ user_emb, float* __restrict__ out)
{
    __shared__ int sX[4 * HIST];

    const int tid = threadIdx.x;
    const int b0  = blockIdx.x * 4;

    const int wave   = tid >> 6;
    const int lane   = tid & 63;
    const int lane16 = lane & 15;
    const int g      = lane >> 4;
    const int b      = __builtin_amdgcn_readfirstlane(b0 + wave);

    // issue y/u loads BEFORE the staging barrier (independent of sX)
    const float4* item4 = reinterpret_cast<const float4*>(item_emb);
    const float4* user4 = reinterpret_cast<const float4*>(user_emb);
    const int yi = y[b];                  // wave-uniform scalar loads
    const int ui = u[b];
    const float4 y4 = item4[(size_t)yi * 16 + lane16];  // fp32, coalesced
    const float4 u4 = user4[(size_t)ui * 16 + lane16];  // fp32, coalesced

    if (tid < 4 * HIST) sX[tid] = X[b0 * HIST + tid];   // coalesced staging
    __syncthreads();

    const float uy = red16_add(dot4(u4, y4));           // exact fp32 u.y

    const int start = (g < 2) ? g * 13 : 26 + (g - 2) * 12;
    const int count = (g < 2) ? 13 : 12;
    const int* wX = sX + wave * HIST;

    // phase 1: issue ALL 13 row-loads back-to-back (13 dest VGPRs)
    unsigned q[13];
    #pragma unroll
    for (int k = 0; k < 13; ++k) {
        const int idx = (k < count) ? wX[start + k] : 0;   // row 0 = zeros (hot line)
        q[k] = item8[(size_t)idx * 16 + lane16];           // 64 B/row, 1 line
    }

    // phase 2: decode + dot + 16-lane reduce
    float wv = -1e30f;
    #pragma unroll
    for (int k = 0; k < 13; ++k) {
        const v2f lo = __builtin_amdgcn_cvt_pk_f32_fp8((int)q[k], false);
        const v2f hi = __builtin_amdgcn_cvt_pk_f32_fp8((int)q[k], true);
        const float w = red16_add(lo.x*y4.x + lo.y*y4.y + hi.x*y4.z + hi.y*y4.w);
        if (k < count && lane16 == k) wv = w;
    }

    float m = red16_max(wv);
    m = fmaxf(m, __shfl_xor(m, 16, 64));
    m = fmaxf(m, __shfl_xor(m, 32, 64));

    const float e = __expf(wv - m);       // invalid slots: exp(-huge)=0
    float s = red16_add(e);
    float t = red16_add(e * wv);
    s += __shfl_xor(s, 16, 64);  s += __shfl_xor(s, 32, 64);
    t += __shfl_xor(t, 16, 64);  t += __shfl_xor(t, 32, 64);

    if (lane == 0) {
        const float logit = t / s + uy;
        out[b] = 1.0f / (1.0f + __expf(-logit));
    }
}

// ---- fp32 fallback if ws is too small ----
__global__ __launch_bounds__(256, 4) void RUM_72980084294375_f32_kernel(
    const int* __restrict__ u, const int* __restrict__ X, const int* __restrict__ y,
    const float* __restrict__ item_emb, const float* __restrict__ user_emb,
    float* __restrict__ out)
{
    __shared__ int sX[4 * HIST];
    const int tid = threadIdx.x;
    const int b0  = blockIdx.x * 4;

    const int wave   = tid >> 6;
    const int lane   = tid & 63;
    const int lane16 = lane & 15;
    const int g      = lane >> 4;
    const int b      = __builtin_amdgcn_readfirstlane(b0 + wave);

    const float4* item4 = reinterpret_cast<const float4*>(item_emb);
    const float4* user4 = reinterpret_cast<const float4*>(user_emb);
    const int yi = y[b];
    const int ui = u[b];
    const float4 y4 = item4[(size_t)yi * 16 + lane16];
    const float4 u4 = user4[(size_t)ui * 16 + lane16];

    if (tid < 4 * HIST) sX[tid] = X[b0 * HIST + tid];
    __syncthreads();

    const float uy = red16_add(dot4(u4, y4));

    const int start = (g < 2) ? g * 13 : 26 + (g - 2) * 12;
    const int count = (g < 2) ? 13 : 12;
    const int* wX = sX + wave * HIST;

    float wv = -1e30f;
    #pragma unroll
    for (int k = 0; k < 13; ++k) {
        const int idx = (k < count) ? wX[start + k] : 0;
        const float4 x4 = item4[(size_t)idx * 16 + lane16];
        const float w = red16_add(dot4(x4, y4));
        if (k < count && lane16 == k) wv = w;
    }

    float m = red16_max(wv);
    m = fmaxf(m, __shfl_xor(m, 16, 64));
    m = fmaxf(m, __shfl_xor(m, 32, 64));

    const float e = __expf(wv - m);
    float s = red16_add(e);
    float t = red16_add(e * wv);
    s += __shfl_xor(s, 16, 64);  s += __shfl_xor(s, 32, 64);
    t += __shfl_xor(t, 16, 64);  t += __shfl_xor(t, 32, 64);

    if (lane == 0) {
        const float logit = t / s + uy;
        out[b] = 1.0f / (1.0f + __expf(-logit));
    }
}

extern "C" void kernel_launch(void* const* d_in, const int* in_sizes, int n_in,
                              void* d_out, int out_size, void* d_ws, size_t ws_size,
                              hipStream_t stream) {
    const int*   u        = (const int*)d_in[0];
    const int*   X        = (const int*)d_in[1];
    const int*   y        = (const int*)d_in[2];
    const float* item_emb = (const float*)d_in[3];
    const float* user_emb = (const float*)d_in[4];
    float*       out      = (float*)d_out;

    const size_t need = (size_t)ITEM_ROWS * EMB;     // 6.4 MB fp8 table

    if (ws_size >= need) {
        const int n8 = ITEM_ROWS * EMB / 8;          // 800008 (divides exactly)
        cvt_fp8_kernel<<<(n8 + 255) / 256, 256, 0, stream>>>(
            (const float4*)item_emb, (uint2*)d_ws, n8);
        RUM_72980084294375_kernel<<<BATCH / 4, 256, 0, stream>>>(
            u, X, y, (const unsigned*)d_ws, item_emb, user_emb, out);
    } else {
        RUM_72980084294375_f32_kernel<<<BATCH / 4, 256, 0, stream>>>(
            u, X, y, item_emb, user_emb, out);
    }
}